// Round 4
// baseline (2202.374 us; speedup 1.0000x reference)
//
#include <hip/hip_runtime.h>

#define NB 32
#define NT 128
#define NU 768
#define ND 768
#define UPB 3
#define NBLK (NU / UPB)   // 256 blocks, one per CU
#define NTHR (256 * UPB)  // 768 threads = 12 waves/CU
#define HPAD 772          // 768 + 4: conflict-free b128 stride

#define AGENT __HIP_MEMORY_SCOPE_AGENT

typedef float f32x4 __attribute__((ext_vector_type(4)));

__device__ __forceinline__ float fexp2(float x) { return __builtin_amdgcn_exp2f(x); }
__device__ __forceinline__ float frcp(float x)  { return __builtin_amdgcn_rcpf(x); }

// x[B,T,D] -> xc[t][c][b][k]  (k = 0..95 within chunk c)
__global__ void make_xc_kernel(const float* __restrict__ x, float* __restrict__ xc) {
  const int t = blockIdx.x;   // 0..127
  const int c = blockIdx.y;   // 0..7
  for (int e = threadIdx.x; e < 32 * 96; e += 256) {
    int b = e / 96, k = e - b * 96;
    xc[(((size_t)t * 8 + c) * 32) * 96 + e] = x[((size_t)b * NT + t) * ND + c * 96 + k];
  }
}

// h0[B,U] is already the transposed-[b][u] layout; copy + zero flags
__global__ void init_h_kernel(const float* __restrict__ h0, float* __restrict__ hT,
                              unsigned int* __restrict__ flags) {
  int i = blockIdx.x * 256 + threadIdx.x;
  if (i < NU * NB) hT[i] = h0[i];
  if (i < NBLK) flags[i] = 0u;
}

// outT[T,U,B] -> out[B,T,U]
__global__ void transpose_out_kernel(const float* __restrict__ outT, float* __restrict__ out) {
  __shared__ float tile[32][33];
  const int t  = blockIdx.x;
  const int u0 = blockIdx.y * 32;
  const int lo = threadIdx.x & 31;
  const int hi = threadIdx.x >> 5;
#pragma unroll
  for (int uu = hi; uu < 32; uu += 8)
    tile[uu][lo] = outT[((size_t)t * NU + u0 + uu) * NB + lo];
  __syncthreads();
#pragma unroll
  for (int bb = hi; bb < 32; bb += 8)
    out[((size_t)bb * NT + t) * NU + u0 + lo] = tile[lo][bb];
}

__global__ void __launch_bounds__(NTHR, 3)
rnn_fused_kernel(const float* __restrict__ xc,
                 const float* __restrict__ wk,
                 const float* __restrict__ wrk,
                 const float* __restrict__ wak,
                 const float* __restrict__ wrak,
                 const float* __restrict__ bias,
                 const float* __restrict__ gpa,
                 const float* __restrict__ gpra,
                 float* hTA, float* hTB,
                 float* __restrict__ outT,
                 unsigned int* flags)
{
  const int tid  = threadIdx.x;
  const int uloc = tid >> 8;        // 0..2
  const int lt   = tid & 255;
  const int b    = lt & 31;
  const int c    = lt >> 5;         // 0..7
  const int d0   = c * 96;
  const int u    = blockIdx.x * UPB + uloc;

  __shared__ __align__(16) float s_ak[UPB][ND], s_k[UPB][ND], s_rak[UPB][ND], s_rk[UPB][ND];
  __shared__ __align__(16) float sh[NB * HPAD];   // h as [b][u], stride 772
  __shared__ float red[UPB][6][4][32];

#pragma unroll
  for (int j = 0; j < UPB; ++j) {
    const int ug = blockIdx.x * UPB + j;
    s_ak [j][tid] = wak [(size_t)ug * ND + tid];
    s_k  [j][tid] = wk  [(size_t)ug * ND + tid];
    s_rak[j][tid] = wrak[(size_t)ug * NU + tid];
    s_rk [j][tid] = wrk [(size_t)ug * NU + tid];
  }
  const float bias_u = bias[u];
  const float ga  = 1.0f / (1.0f + __expf(-gpa[0]));
  const float gra = 1.0f / (1.0f + __expf(-gpra[0]));

  // stage-copy mapping: thread tid handles flats j*3072 + 4*tid .. +3
  const int tq = tid / 192;              // b offset within chunk group
  const int ur = 4 * tid - 768 * tq;     // (4*tid) % 768

  const float* hcurT = hTA;
  float* hnextT = hTB;
  const float LOG2E = 1.4426950408889634f;

  for (int t = 0; t < NT; ++t) {
    // ---- stage h (global, sc1-coherent) -> LDS sh[b][u] ----
    f32x4 hr[8];
#pragma unroll
    for (int j = 0; j < 8; ++j) {
      const float* p = hcurT + j * 3072 + 4 * tid;
      asm volatile("global_load_dwordx4 %0, %1, off sc1"
                   : "=&v"(hr[j]) : "v"(p) : "memory");
    }
    asm volatile("s_waitcnt vmcnt(0)" ::: "memory");
    __builtin_amdgcn_sched_barrier(0);
#pragma unroll
    for (int j = 0; j < 8; ++j)
      *(f32x4*)&sh[(4 * j + tq) * HPAD + ur] = hr[j];
    __syncthreads();

    const float hu = sh[b * HPAD + u];
    const float hs = hu * LOG2E;

    float s_a = 0.f, n_a = 0.f, l_a = 0.f;
    float s_r = 0.f, n_r = 0.f, l_r = 0.f;
    const float* xp  = xc + ((size_t)(t * 8 + c) * 32 + b) * 96;
    const float* hp  = &sh[b * HPAD + d0];
    const float* ap  = &s_ak [uloc][d0];
    const float* kp  = &s_k  [uloc][d0];
    const float* rap = &s_rak[uloc][d0];
    const float* rkp = &s_rk [uloc][d0];

#pragma unroll 4
    for (int k4 = 0; k4 < 24; ++k4) {
      f32x4 xv  = *(const f32x4*)(xp  + 4 * k4);   // global (plain, L2)
      f32x4 hv  = *(const f32x4*)(hp  + 4 * k4);   // LDS
      f32x4 av  = *(const f32x4*)(ap  + 4 * k4);   // LDS broadcast
      f32x4 kv  = *(const f32x4*)(kp  + 4 * k4);
      f32x4 rav = *(const f32x4*)(rap + 4 * k4);
      f32x4 rkv = *(const f32x4*)(rkp + 4 * k4);
#pragma unroll
      for (int j = 0; j < 4; ++j) {
        float e  = fexp2(hs * xv[j] * av[j]);
        float kx = kv[j] * xv[j];
        s_a += e; l_a += kx; n_a = fmaf(e, kx, n_a);
        float er = fexp2(hs * hv[j] * rav[j]);
        float kh = rkv[j] * hv[j];
        s_r += er; l_r += kh; n_r = fmaf(er, kh, n_r);
      }
    }

    // ---- reduce 8 chunks: c-pair via shfl(32), 4 waves via LDS ----
    float v0 = s_a + __shfl_xor(s_a, 32);
    float v1 = n_a + __shfl_xor(n_a, 32);
    float v2 = l_a + __shfl_xor(l_a, 32);
    float v3 = s_r + __shfl_xor(s_r, 32);
    float v4 = n_r + __shfl_xor(n_r, 32);
    float v5 = l_r + __shfl_xor(l_r, 32);
    const int w = (tid >> 6) & 3;
    if ((tid & 63) < 32) {
      red[uloc][0][w][b] = v0; red[uloc][1][w][b] = v1; red[uloc][2][w][b] = v2;
      red[uloc][3][w][b] = v3; red[uloc][4][w][b] = v4; red[uloc][5][w][b] = v5;
    }
    __syncthreads();

    if (lt < 32) {
      float r0 = red[uloc][0][0][b] + red[uloc][0][1][b] + red[uloc][0][2][b] + red[uloc][0][3][b];
      float r1 = red[uloc][1][0][b] + red[uloc][1][1][b] + red[uloc][1][2][b] + red[uloc][1][3][b];
      float r2 = red[uloc][2][0][b] + red[uloc][2][1][b] + red[uloc][2][2][b] + red[uloc][2][3][b];
      float r3 = red[uloc][3][0][b] + red[uloc][3][1][b] + red[uloc][3][2][b] + red[uloc][3][3][b];
      float r4 = red[uloc][4][0][b] + red[uloc][4][1][b] + red[uloc][4][2][b] + red[uloc][4][3][b];
      float r5 = red[uloc][5][0][b] + red[uloc][5][1][b] + red[uloc][5][2][b] + red[uloc][5][3][b];
      float hh = r2 + bias_u + ga * (r1 * frcp(r0));
      float z  = hh + r5 + gra * (r4 * frcp(r3));
      float ex = fexp2(z * 2.8853900817779268f);   // tanh(z) = 1 - 2/(e^{2z}+1)
      float o  = 1.0f - 2.0f * frcp(ex + 1.0f);
      __hip_atomic_store(&hnextT[b * NU + u], o, __ATOMIC_RELAXED, AGENT);
      outT[((size_t)t * NU + u) * NB + b] = o;
    }

    if (t != NT - 1) {
      asm volatile("s_waitcnt vmcnt(0)" ::: "memory");
      __syncthreads();   // all h-stores drained before flag publication
      if (tid == 0)
        __hip_atomic_store(&flags[blockIdx.x], (unsigned)(t + 1), __ATOMIC_RELAXED, AGENT);
      if (tid < NBLK) {
        const unsigned tgt = (unsigned)(t + 1);
        while (__hip_atomic_load(&flags[tid], __ATOMIC_RELAXED, AGENT) < tgt)
          __builtin_amdgcn_s_sleep(2);
      }
      __syncthreads();
    }
    { const float* tmp = hcurT; hcurT = hnextT; hnextT = (float*)tmp; }
  }
}

extern "C" void kernel_launch(void* const* d_in, const int* in_sizes, int n_in,
                              void* d_out, int out_size, void* d_ws, size_t ws_size,
                              hipStream_t stream) {
  const float* x    = (const float*)d_in[0];
  const float* h0   = (const float*)d_in[1];
  const float* wk   = (const float*)d_in[2];
  const float* wrk  = (const float*)d_in[3];
  const float* wak  = (const float*)d_in[4];
  const float* wrak = (const float*)d_in[5];
  const float* bias = (const float*)d_in[6];
  const float* gpa  = (const float*)d_in[7];
  const float* gpra = (const float*)d_in[8];
  float* out = (float*)d_out;

  float* xc   = (float*)d_ws;                       // 12.58 MB
  float* outT = xc + (size_t)NT * ND * NB;          // 12.58 MB
  float* hTA  = outT + (size_t)NT * NU * NB;        // 96 KB
  float* hTB  = hTA + NU * NB;                      // 96 KB
  unsigned int* flags = (unsigned int*)(hTB + NU * NB);

  make_xc_kernel<<<dim3(NT, 8), 256, 0, stream>>>(x, xc);
  init_h_kernel<<<(NU * NB + 255) / 256, 256, 0, stream>>>(h0, hTA, flags);
  rnn_fused_kernel<<<NBLK, NTHR, 0, stream>>>(xc, wk, wrk, wak, wrak, bias, gpa, gpra,
                                              hTA, hTB, outT, flags);
  transpose_out_kernel<<<dim3(NT, NU / 32), 256, 0, stream>>>(outT, out);
}